// Round 6
// baseline (102.566 us; speedup 1.0000x reference)
//
#include <hip/hip_runtime.h>

// DAG reachability closure from node 0. N=8192 nodes, left/right child in
// [-1, N). Reference = N relaxation steps == transitive closure from node 0.
//
// FULLY ASYNC chaotic propagation — no barriers, no flags, no LDS edge table:
//   - thread t owns nodes [8t,8t+8); their (L,R) edges are PRELOADED INTO
//     REGISTERS (coalesced int4), so expansion never touches an edge table.
//     Per-hop critical path: child atomicOr lands -> owner's free-running
//     poll read sees it (~150cy) -> owner issues grandchildren ors from
//     registers (~30cy VALU). ~350cy/hop vs ~1500+ for barriered passes.
//   - vis bitmask (1 KB) + ONE outstanding-work counter s_out in LDS.
//   - exact async termination: expander atomicAdd(+m) BEFORE issuing its m
//     child ors (same-wave DS ops execute in order, so the +m lands first),
//     then one atomicAdd(-(dups+expanded)) after the or-returns. Invariant:
//     s_out >= 1 while any set bit is unexpanded or any or is in flight;
//     s_out == 0 exactly at quiescence (1 + firstsets - expanded = 0).
//     All threads poll s_out (same-address wave read = broadcast) and exit.
//   - or-returns batched: issue all (fire-and-forget), one wait, then count
//     dups — return latency never serializes or issue.
// Output: bool mask -> INT32 0/1 (harness reads bool output as int32).

#define NMAX   8192
#define BLK    1024
#define NWORDS (NMAX / 32)

__global__ __launch_bounds__(BLK) void dag_reach_kernel(
    const int* __restrict__ left,
    const int* __restrict__ right,
    int* __restrict__ out,
    int n)
{
    __shared__ unsigned int vis[NWORDS];   // 1 KB reachable bitmask
    __shared__ int s_out;                  // outstanding-work counter

    const int tid  = threadIdx.x;
    const int base = tid * 8;

    // ---- Preload my 8 nodes' edges into registers (coalesced int4) ----
    int L[8], R[8];
    if (base + 7 < n) {
        int4 l0 = *reinterpret_cast<const int4*>(left  + base);
        int4 l1 = *reinterpret_cast<const int4*>(left  + base + 4);
        int4 r0 = *reinterpret_cast<const int4*>(right + base);
        int4 r1 = *reinterpret_cast<const int4*>(right + base + 4);
        L[0]=l0.x; L[1]=l0.y; L[2]=l0.z; L[3]=l0.w;
        L[4]=l1.x; L[5]=l1.y; L[6]=l1.z; L[7]=l1.w;
        R[0]=r0.x; R[1]=r0.y; R[2]=r0.z; R[3]=r0.w;
        R[4]=r1.x; R[5]=r1.y; R[6]=r1.z; R[7]=r1.w;
    } else {
        #pragma unroll
        for (int j = 0; j < 8; ++j) {
            L[j] = (base + j < n) ? left[base + j]  : -1;
            R[j] = (base + j < n) ? right[base + j] : -1;
        }
    }

    if (tid < NWORDS) vis[tid] = 0u;
    if (tid == 0) { vis[0] = 1u; s_out = 1; }   // seed: node 0 set, 1 pending
    __syncthreads();                            // the ONLY barrier

    const int word  = tid >> 2;                 // my vis word
    const int shift = (tid & 3) * 8;            // my byte within it
    unsigned int expanded = 0u;

    for (;;) {
        // Two independent DS reads, one latency. Same-address lanes broadcast.
        unsigned int w = __atomic_load_n(&vis[word], __ATOMIC_RELAXED);
        int          o = __atomic_load_n(&s_out,     __ATOMIC_RELAXED);
        unsigned int pend = ((w >> shift) & 0xFFu) & ~expanded;

        if (pend) {
            expanded |= pend;

            // m = #valid children among pending bits (pure VALU, registers).
            int m = 0;
            #pragma unroll
            for (int j = 0; j < 8; ++j) {
                if ((pend >> j) & 1u) m += (L[j] >= 0) + (R[j] >= 0);
            }
            if (m) atomicAdd(&s_out, m);        // publish BEFORE the ors land

            // Issue all ors fire-and-forget (returns consumed later, batched).
            unsigned int oL[8], oR[8];
            #pragma unroll
            for (int j = 0; j < 8; ++j) {
                const bool pj = (pend >> j) & 1u;
                if (pj && L[j] >= 0)
                    oL[j] = atomicOr(&vis[L[j] >> 5], 1u << (L[j] & 31));
                if (pj && R[j] >= 0)
                    oR[j] = atomicOr(&vis[R[j] >> 5], 1u << (R[j] & 31));
            }
            // One wait here (first use), then count duplicates.
            int d = 0;
            #pragma unroll
            for (int j = 0; j < 8; ++j) {
                const bool pj = (pend >> j) & 1u;
                if (pj && L[j] >= 0) d += (oL[j] >> (L[j] & 31)) & 1u;
                if (pj && R[j] >= 0) d += (oR[j] >> (R[j] & 31)) & 1u;
            }
            atomicAdd(&s_out, -(d + __popc(pend)));
        } else if (o == 0) {
            break;          // quiescent: every set bit expanded, none in flight
        }
    }

    // ---- vis is final; write bool mask as int32 0/1 (coalesced int4) ----
    for (int i = 4 * tid; i < n; i += 4 * BLK) {
        const unsigned w = vis[i >> 5];
        const int b = i & 31;
        *reinterpret_cast<int4*>(out + i) =
            make_int4((int)((w >> (b + 0)) & 1u),
                      (int)((w >> (b + 1)) & 1u),
                      (int)((w >> (b + 2)) & 1u),
                      (int)((w >> (b + 3)) & 1u));
    }
}

extern "C" void kernel_launch(void* const* d_in, const int* in_sizes, int n_in,
                              void* d_out, int out_size, void* d_ws, size_t ws_size,
                              hipStream_t stream)
{
    // inputs: 0 = thresholds (f32, UNUSED by reference), 1 = left (i32), 2 = right (i32)
    const int* left  = (const int*)d_in[1];
    const int* right = (const int*)d_in[2];
    int* out = (int*)d_out;
    const int n = in_sizes[1];

    dag_reach_kernel<<<1, BLK, 0, stream>>>(left, right, out, n);
}

// Round 7
// 89.227 us; speedup vs baseline: 1.1495x; 1.1495x over previous
//
#include <hip/hip_runtime.h>

// DAG reachability closure from node 0. N=8192 nodes, left/right child in
// [-1, N). Reference = N relaxation steps == transitive closure from node 0.
//
// Calibration (R0-R6, offset=52us exact): all barriered chaotic variants sit
// at ~1200 cy/pass x ~35 passes because each "fix" traded one serial-path
// item for another (extra INNER reads vs extra barrier vs wave count).
// This version makes the per-pass critical path MINIMAL:
//   - 256 threads = 4 waves (cheapest barrier), thread t owns vis word t
//     (nodes [32t,32t+32)); INNER=1; ONE barrier/pass (rotating mod-3 flag,
//     protocol proven in R4).
//   - pass-top issues TWO independent LDS reads (own vis word + flag[prev])
//     sharing one lgkmcnt wait; break decision lags one pass (1 extra cheap
//     pass instead of a serial post-barrier flag read every pass).
//   - edges PRELOADED INTO REGISTERS (64 VGPR, statically indexed via fully
//     unrolled byte-gated expansion): expansion path = pure VALU + fire-and-
//     forget LDS atomicOr, ZERO LDS reads. Per-pass serial path ~= 150cy
//     (read) + ~50 (VALU) + ~200 (4-wave barrier) ~= 450 cy vs ~1200 before.
//   - LDS total: 1 KB bitmask + 12 B flags (no edge table).
// Output: bool mask -> INT32 0/1 (harness reads bool output as int32).

#define NMAX 8192
#define BLK  256
#define NW   (NMAX / 32)   // 256 vis words, one per thread

__global__ __launch_bounds__(BLK) void dag_reach_kernel(
    const int* __restrict__ left,
    const int* __restrict__ right,
    int* __restrict__ out,
    int n)
{
    __shared__ unsigned int vis[NW];   // 1 KB reachable bitmask
    __shared__ int s_flag[3];          // rotating change flags

    const int tid  = threadIdx.x;
    const int base = tid * 32;         // my 32 nodes

    // ---- Preload my 32 nodes' edges into registers (8+8 int4 loads) ----
    int L[32], R[32];
    if (base + 31 < n) {
        #pragma unroll
        for (int k = 0; k < 8; ++k) {
            int4 l = *reinterpret_cast<const int4*>(left  + base + 4 * k);
            int4 r = *reinterpret_cast<const int4*>(right + base + 4 * k);
            L[4*k+0] = l.x; L[4*k+1] = l.y; L[4*k+2] = l.z; L[4*k+3] = l.w;
            R[4*k+0] = r.x; R[4*k+1] = r.y; R[4*k+2] = r.z; R[4*k+3] = r.w;
        }
    } else {
        #pragma unroll
        for (int j = 0; j < 32; ++j) {
            L[j] = (base + j < n) ? left[base + j]  : -1;
            R[j] = (base + j < n) ? right[base + j] : -1;
        }
    }

    vis[tid] = (tid == 0) ? 1u : 0u;            // seed: node 0 reachable
    if (tid < 3) s_flag[tid] = (tid == 2);      // prime flag[prev of pass 0]
    __syncthreads();

    volatile unsigned int* vv = vis;
    volatile int*          vf = s_flag;
    unsigned int expanded = 0u;
    int cur = 0;

    for (;;) {
        const int prv = (cur == 0) ? 2 : cur - 1;
        // Two independent LDS reads -> one lgkmcnt wait.
        const unsigned int w = vv[tid];
        const int          f = vf[prv];
        if (!f) break;                          // uniform (post-barrier stable)

        const unsigned int pend = w & ~expanded;
        int ch = 0;
        if (pend) {
            ch = 1;
            expanded |= pend;
            // Byte-gated fully-unrolled expansion: static register indexing,
            // fire-and-forget atomics (results unused -> off critical path).
            #pragma unroll
            for (int b = 0; b < 4; ++b) {
                if ((pend >> (8 * b)) & 0xFFu) {
                    #pragma unroll
                    for (int j = 8 * b; j < 8 * b + 8; ++j) {
                        if ((pend >> j) & 1u) {
                            const int l = L[j], r = R[j];
                            if (l >= 0) atomicOr(&vis[l >> 5], 1u << (l & 31));
                            if (r >= 0) atomicOr(&vis[r >> 5], 1u << (r & 31));
                        }
                    }
                }
            }
        }

        const int nxt = (cur == 2) ? 0 : cur + 1;
        const int wch = __any(ch);              // all lanes participate
        if ((tid & 63) == 0) {
            s_flag[nxt] = 0;                    // reset slot for next pass
            if (wch) s_flag[cur] = 1;           // publish "changed this pass"
        }
        __syncthreads();                        // the ONLY barrier per pass
        cur = nxt;
    }

    // ---- vis final; write bool mask as int32 0/1 (coalesced int4) ----
    for (int i = 4 * tid; i < n; i += 4 * BLK) {
        const unsigned w = vis[i >> 5];
        const int b = i & 31;
        *reinterpret_cast<int4*>(out + i) =
            make_int4((int)((w >> (b + 0)) & 1u),
                      (int)((w >> (b + 1)) & 1u),
                      (int)((w >> (b + 2)) & 1u),
                      (int)((w >> (b + 3)) & 1u));
    }
}

extern "C" void kernel_launch(void* const* d_in, const int* in_sizes, int n_in,
                              void* d_out, int out_size, void* d_ws, size_t ws_size,
                              hipStream_t stream)
{
    // inputs: 0 = thresholds (f32, UNUSED by reference), 1 = left (i32), 2 = right (i32)
    const int* left  = (const int*)d_in[1];
    const int* right = (const int*)d_in[2];
    int* out = (int*)d_out;
    const int n = in_sizes[1];

    dag_reach_kernel<<<1, BLK, 0, stream>>>(left, right, out, n);
}

// Round 8
// 75.623 us; speedup vs baseline: 1.3563x; 1.1799x over previous
//
#include <hip/hip_runtime.h>

// DAG reachability closure from node 0. N=8192 nodes, left/right child in
// [-1, N). Reference = N relaxation steps == transitive closure from node 0.
//
// R0's proven core (the session best: 1024 threads = 16 waves, thread t owns
// nodes [8t,8t+8), LDS int2 edge table, __ffs-peel work-scaled expansion,
// fire-and-forget LDS atomicOr) with ONLY the sync scaffolding changed:
//   - ONE barrier per pass (was 2) via rotating mod-3 flag: end of pass p
//     resets flag[p+1], sets flag[p] if changed; barrier; pass p+1 reads
//     flag[p]. Each slot's reset/write/read are in consecutive passes,
//     separated by barriers -> race-free; break decision is uniform.
//   - flag[prev] read FOLDED into the pass-top vis read: two independent
//     LDS reads share one lgkmcnt wait. Break lags one pass (one cheap
//     extra pass) instead of a serial ~150cy post-barrier flag read.
//   - INNER=1 (R4's INNER=4 added 3 serial dependent reads/pass: regression).
//   - NOT register-resident edges: R7 proved the unrolled exec-masked ladder
//     costs ~300 instr/pass regardless of pending density. ffs-peel over the
//     LDS table scales with actual work.
// Output: bool mask -> INT32 0/1 (harness reads bool output as int32).

#define NMAX   8192
#define BLK    1024
#define NWORDS (NMAX / 32)

__global__ __launch_bounds__(BLK) void dag_reach_kernel(
    const int* __restrict__ left,
    const int* __restrict__ right,
    int* __restrict__ out,
    int n)
{
    __shared__ int2 sLR[NMAX];               // 64 KB: packed (left, right)
    __shared__ unsigned int reach[NWORDS];   // 1 KB: reachable bitmask
    __shared__ int s_flag[3];                // rotating change flags

    const int tid  = threadIdx.x;
    const int base = tid * 8;                // my 8 nodes

    // ---- Stage edges: int4 global loads, packed int2 LDS writes ----
    if (base + 7 < n) {
        int4 l0 = *reinterpret_cast<const int4*>(left  + base);
        int4 l1 = *reinterpret_cast<const int4*>(left  + base + 4);
        int4 r0 = *reinterpret_cast<const int4*>(right + base);
        int4 r1 = *reinterpret_cast<const int4*>(right + base + 4);
        sLR[base + 0] = make_int2(l0.x, r0.x);
        sLR[base + 1] = make_int2(l0.y, r0.y);
        sLR[base + 2] = make_int2(l0.z, r0.z);
        sLR[base + 3] = make_int2(l0.w, r0.w);
        sLR[base + 4] = make_int2(l1.x, r1.x);
        sLR[base + 5] = make_int2(l1.y, r1.y);
        sLR[base + 6] = make_int2(l1.z, r1.z);
        sLR[base + 7] = make_int2(l1.w, r1.w);
    } else {
        for (int k = base; k < n; ++k) sLR[k] = make_int2(left[k], right[k]);
    }
    if (tid < NWORDS) reach[tid] = (tid == 0) ? 1u : 0u;
    if (tid < 3)      s_flag[tid] = (tid == 2) ? 1 : 0;  // prime flag[prev]
    __syncthreads();

    const int word_idx = tid >> 2;           // my reach word
    const int shift    = (tid & 3) * 8;      // my byte within it
    unsigned int expanded = 0u;
    volatile unsigned int* vv = reach;
    volatile int*          vf = s_flag;
    int cur = 0;

    for (;;) {
        const int prv = (cur == 0) ? 2 : cur - 1;
        // Two independent LDS reads -> one lgkmcnt wait.
        const unsigned int w = vv[word_idx];
        const int          f = vf[prv];
        if (!f) break;                       // uniform: fixpoint (lagged 1 pass)

        unsigned int pend = ((w >> shift) & 0xFFu) & ~expanded;
        int ch = 0;
        if (pend) {
            ch = 1;
            expanded |= pend;
            while (pend) {
                // peel up to 4 pending bits -> 4 independent ds_read_b64
                int b0 = __ffs(pend) - 1; pend &= pend - 1;
                int b1 = -1, b2 = -1, b3 = -1;
                if (pend) { b1 = __ffs(pend) - 1; pend &= pend - 1;
                    if (pend) { b2 = __ffs(pend) - 1; pend &= pend - 1;
                        if (pend) { b3 = __ffs(pend) - 1; pend &= pend - 1; } } }
                int2 e0 = sLR[base + b0];
                int2 e1 = sLR[base + (b1 < 0 ? b0 : b1)];
                int2 e2 = sLR[base + (b2 < 0 ? b0 : b2)];
                int2 e3 = sLR[base + (b3 < 0 ? b0 : b3)];
                if (e0.x >= 0) atomicOr(&reach[e0.x >> 5], 1u << (e0.x & 31));
                if (e0.y >= 0) atomicOr(&reach[e0.y >> 5], 1u << (e0.y & 31));
                if (b1 >= 0) {
                    if (e1.x >= 0) atomicOr(&reach[e1.x >> 5], 1u << (e1.x & 31));
                    if (e1.y >= 0) atomicOr(&reach[e1.y >> 5], 1u << (e1.y & 31));
                }
                if (b2 >= 0) {
                    if (e2.x >= 0) atomicOr(&reach[e2.x >> 5], 1u << (e2.x & 31));
                    if (e2.y >= 0) atomicOr(&reach[e2.y >> 5], 1u << (e2.y & 31));
                }
                if (b3 >= 0) {
                    if (e3.x >= 0) atomicOr(&reach[e3.x >> 5], 1u << (e3.x & 31));
                    if (e3.y >= 0) atomicOr(&reach[e3.y >> 5], 1u << (e3.y & 31));
                }
            }
        }

        const int nxt = (cur == 2) ? 0 : cur + 1;
        const int wch = __any(ch);           // all 64 lanes participate
        if ((tid & 63) == 0) {
            s_flag[nxt] = 0;                 // reset slot for pass after next
            if (wch) s_flag[cur] = 1;        // publish "changed this pass"
        }
        __syncthreads();                     // the ONLY barrier per pass
        cur = nxt;
    }

    // ---- Write bool mask as int32 0/1 (16 B per lane, coalesced) ----
    for (int i = 4 * tid; i < n; i += 4 * BLK) {
        const unsigned w = reach[i >> 5];
        const int b = i & 31;
        *reinterpret_cast<int4*>(out + i) =
            make_int4((int)((w >> (b + 0)) & 1u),
                      (int)((w >> (b + 1)) & 1u),
                      (int)((w >> (b + 2)) & 1u),
                      (int)((w >> (b + 3)) & 1u));
    }
}

extern "C" void kernel_launch(void* const* d_in, const int* in_sizes, int n_in,
                              void* d_out, int out_size, void* d_ws, size_t ws_size,
                              hipStream_t stream)
{
    // inputs: 0 = thresholds (f32, UNUSED by reference), 1 = left (i32), 2 = right (i32)
    const int* left  = (const int*)d_in[1];
    const int* right = (const int*)d_in[2];
    int* out = (int*)d_out;
    const int n = in_sizes[1];

    dag_reach_kernel<<<1, BLK, 0, stream>>>(left, right, out, n);
}